// Round 1
// 971.409 us; speedup vs baseline: 2.0550x; 2.0550x over previous
//
#include <hip/hip_runtime.h>

// Problem: x (8,2048,512) f32, embed (1,8192,512) f32 (rows unit-norm).
// dist[r][c] = dot(x_row[r], embed[c])  -> (16384, 8192)
// ind[r] = argmax_c dist[r][c]
// outputs (concat f32): quantize = embed[ind] (8*2048*512) | ind as float (16384) | dist (16384*8192)
//
// Strategy: fp32 GEMM emulated on the bf16 matrix pipe via hi/lo split:
//   a*b ~= a_hi*b_hi + a_lo*b_hi + a_hi*b_lo   (3 bf16 GEMM terms, virtual K=1536)
// m97-structure 128x128 tile, global_load_lds width=16, mfma_f32_16x16x32_bf16,
// fused per-tile argmax epilogue; finalize kernel unchanged.

#define NROWS   16384
#define NCOLS   8192
#define KDIM    512
#define KSPLIT  1024      // per-row split layout: [0,512)=hi, [512,1024)=lo (bf16)
#define NCTILES 64        // 8192 / 128

#define BM 128
#define BN 128
#define BK 32
#define NSTEPS 48         // 3 segments * (512/32)

typedef float f32x4 __attribute__((ext_vector_type(4)));
typedef short s16x8 __attribute__((ext_vector_type(8)));

static __device__ __forceinline__ unsigned short f2bf_rne(float f) {
    unsigned u = __float_as_uint(f);
    u = (u + 0x7FFFu + ((u >> 16) & 1u)) >> 16;   // round-to-nearest-even
    return (unsigned short)u;
}
static __device__ __forceinline__ float bf2f(unsigned short h) {
    return __uint_as_float(((unsigned)h) << 16);
}

#define GLOAD_LDS16(g, l)                                                              \
    __builtin_amdgcn_global_load_lds((const __attribute__((address_space(1))) void*)(g), \
                                     (__attribute__((address_space(3))) void*)(l), 16, 0, 0)

// ---------------- kernel 0: fp32 -> (hi,lo) bf16 split ----------------
// grid: NROWS + NCOLS blocks, 128 threads; one 512-float row per block.
__global__ __launch_bounds__(128) void split_kernel(
    const float* __restrict__ x, const float* __restrict__ embed,
    unsigned short* __restrict__ A, unsigned short* __restrict__ B)
{
    int row = blockIdx.x;
    const float* src;
    unsigned short* dst;
    if (row < NROWS) { src = x + (size_t)row * KDIM;     dst = A + (size_t)row * KSPLIT; }
    else { row -= NROWS; src = embed + (size_t)row * KDIM; dst = B + (size_t)row * KSPLIT; }

    const int t = threadIdx.x;                 // 0..127, one float4 each
    const float4 v = ((const float4*)src)[t];
    const float f[4] = {v.x, v.y, v.z, v.w};
    unsigned short h[4], l[4];
#pragma unroll
    for (int i = 0; i < 4; i++) {
        h[i] = f2bf_rne(f[i]);
        l[i] = f2bf_rne(f[i] - bf2f(h[i]));
    }
    *(ushort4*)(dst + t * 4)        = make_ushort4(h[0], h[1], h[2], h[3]);
    *(ushort4*)(dst + KDIM + t * 4) = make_ushort4(l[0], l[1], l[2], l[3]);
}

// ---------------- kernel 1: bf16-split MFMA GEMM + per-(row, col-tile) argmax ----------------
// 256 threads = 4 waves (2x2), each wave computes a 64x64 sub-tile as 4x4 16x16 fragments.
__global__ __launch_bounds__(256, 3) void gemm_bf16_argmax(
    const unsigned short* __restrict__ A,   // [16384][1024] bf16 (hi|lo)
    const unsigned short* __restrict__ B,   // [8192][1024]  bf16 (hi|lo)
    float* __restrict__ dist,               // [16384][8192]
    float* __restrict__ ws_val,             // [16384*64]
    int*   __restrict__ ws_idx)             // [16384*64]
{
    __shared__ unsigned short As[BM * BK];  // [row][k] row-major, 8 KB
    __shared__ unsigned short Bs[BN * BK];  // [col][k] row-major, 8 KB
    __shared__ float redV[BM * 2];
    __shared__ int   redI[BM * 2];

    const int tid   = threadIdx.x;
    const int lane  = tid & 63;
    const int wid   = tid >> 6;
    const int waveM = wid >> 1;             // 0..1
    const int waveN = wid & 1;              // 0..1
    const int q     = lane >> 4;            // 0..3 (k-chunk / C-row group)
    const int lc    = lane & 15;            // fragment row (A) / col (B,C)
    const int rowBase = blockIdx.y * BM;
    const int colBase = blockIdx.x * BN;

    // staging map: thread tid -> LDS bytes [tid*16, +16), i.e. row tid>>2, k-chunk (tid&3)*8
    const int srow   = tid >> 2;            // 0..63
    const int schunk = (tid & 3) * 8;       // bf16 elements within the 32-wide k window
    const unsigned short* Ag = A + (size_t)(rowBase + srow) * KSPLIT + schunk;
    const unsigned short* Bg = B + (size_t)(colBase + srow) * KSPLIT + schunk;
    unsigned short* AsW = &As[tid * 8];
    unsigned short* BsW = &Bs[tid * 8];

    f32x4 acc[4][4];
#pragma unroll
    for (int m = 0; m < 4; m++)
#pragma unroll
        for (int n = 0; n < 4; n++) acc[m][n] = (f32x4){0.f, 0.f, 0.f, 0.f};

    for (int s = 0; s < NSTEPS; s++) {
        const int seg  = s >> 4;                    // 0: hi*hi  1: lo*hi  2: hi*lo
        const int kb   = (s & 15) * BK;
        const int aOff = (seg == 1) ? KDIM : 0;
        const int bOff = (seg == 2) ? KDIM : 0;

        __syncthreads();                            // prior step done reading LDS
        GLOAD_LDS16(Ag + aOff + kb, AsW);
        GLOAD_LDS16(Ag + aOff + kb + (size_t)64 * KSPLIT, AsW + 64 * BK);
        GLOAD_LDS16(Bg + bOff + kb, BsW);
        GLOAD_LDS16(Bg + bOff + kb + (size_t)64 * KSPLIT, BsW + 64 * BK);
        __syncthreads();                            // vmcnt drained -> tiles visible

        s16x8 af[4], bfr[4];
#pragma unroll
        for (int m = 0; m < 4; m++) {
            const int r = waveM * 64 + m * 16 + lc;
            af[m] = *(const s16x8*)&As[r * BK + q * 8];
        }
#pragma unroll
        for (int n = 0; n < 4; n++) {
            const int c = waveN * 64 + n * 16 + lc;
            bfr[n] = *(const s16x8*)&Bs[c * BK + q * 8];
        }
#pragma unroll
        for (int m = 0; m < 4; m++)
#pragma unroll
            for (int n = 0; n < 4; n++)
                acc[m][n] = __builtin_amdgcn_mfma_f32_16x16x32_bf16(af[m], bfr[n], acc[m][n], 0, 0, 0);
    }

    // ---- dist write: C/D layout col=lane&15, row=(lane>>4)*4+reg (m89/m91-verified) ----
    // 16 lanes write 64B contiguous per store inst; nontemporal to keep L2 for operands.
#pragma unroll
    for (int m = 0; m < 4; m++) {
        const int r0 = rowBase + waveM * 64 + m * 16 + q * 4;
#pragma unroll
        for (int reg = 0; reg < 4; reg++) {
            float* dp = dist + (size_t)(r0 + reg) * NCOLS + colBase + waveN * 64 + lc;
#pragma unroll
            for (int n = 0; n < 4; n++)
                __builtin_nontemporal_store(acc[m][n][reg], dp + n * 16);
        }
    }

    // ---- fused argmax over the 128-col tile ----
#pragma unroll
    for (int m = 0; m < 4; m++) {
#pragma unroll
        for (int reg = 0; reg < 4; reg++) {
            float v = acc[m][0][reg];
            int   c = colBase + waveN * 64 + lc;          // n = 0
#pragma unroll
            for (int n = 1; n < 4; n++) {                 // ascending col => strict > keeps lowest idx
                const float vv = acc[m][n][reg];
                if (vv > v) { v = vv; c = colBase + waveN * 64 + n * 16 + lc; }
            }
            // butterfly across the 16 lanes sharing this row (masks < 16 keep q fixed)
#pragma unroll
            for (int off = 1; off < 16; off <<= 1) {
                const float ov = __shfl_xor(v, off);
                const int   oc = __shfl_xor(c, off);
                if (ov > v || (ov == v && oc < c)) { v = ov; c = oc; }
            }
            if (lc == 0) {
                const int tr = waveM * 64 + m * 16 + q * 4 + reg;   // 0..127
                redV[tr * 2 + waveN] = v;
                redI[tr * 2 + waveN] = c;
            }
        }
    }
    __syncthreads();

    if (tid < BM) {
        float v = redV[tid * 2]; int c = redI[tid * 2];
        const float v1 = redV[tid * 2 + 1];               // waveN=1 cols are always higher
        if (v1 > v) { v = v1; c = redI[tid * 2 + 1]; }
        const int r = rowBase + tid;
        ws_val[(size_t)r * NCTILES + blockIdx.x] = v;
        ws_idx[(size_t)r * NCTILES + blockIdx.x] = c;
    }
}

// ---------------- fallback: previous fp32 VALU GEMM (used only if ws too small) ----------------
__global__ __launch_bounds__(256, 2) void gemm_argmax_f32(
    const float* __restrict__ x, const float* __restrict__ embed,
    float* __restrict__ dist, float* __restrict__ ws_val, int* __restrict__ ws_idx)
{
    __shared__ float As[16][BM + 4];
    __shared__ float Bs[16][BN + 4];
    __shared__ float redV[BM * 16];
    __shared__ int   redI[BM * 16];

    const int tid = threadIdx.x;
    const int tx  = tid & 15;
    const int ty  = tid >> 4;
    const int rowBase = blockIdx.y * BM;
    const int colBase = blockIdx.x * BN;
    const int lrow = tid >> 2;
    const int lc   = tid & 3;

    const float* Aptr = x     + (size_t)(rowBase + lrow) * KDIM + lc * 4;
    const float* Bptr = embed + (size_t)(colBase + lrow) * KDIM + lc * 4;

    float acc[8][8];
#pragma unroll
    for (int i = 0; i < 8; i++)
#pragma unroll
        for (int j = 0; j < 8; j++) acc[i][j] = 0.0f;

    for (int kb = 0; kb < KDIM; kb += 16) {
        const float4 a0 = *(const float4*)(Aptr + kb);
        const float4 a1 = *(const float4*)(Aptr + kb + (size_t)64 * KDIM);
        const float4 b0 = *(const float4*)(Bptr + kb);
        const float4 b1 = *(const float4*)(Bptr + kb + (size_t)64 * KDIM);
        __syncthreads();
        const int k0 = lc * 4;
        As[k0 + 0][lrow] = a0.x; As[k0 + 1][lrow] = a0.y;
        As[k0 + 2][lrow] = a0.z; As[k0 + 3][lrow] = a0.w;
        As[k0 + 0][lrow + 64] = a1.x; As[k0 + 1][lrow + 64] = a1.y;
        As[k0 + 2][lrow + 64] = a1.z; As[k0 + 3][lrow + 64] = a1.w;
        Bs[k0 + 0][lrow] = b0.x; Bs[k0 + 1][lrow] = b0.y;
        Bs[k0 + 2][lrow] = b0.z; Bs[k0 + 3][lrow] = b0.w;
        Bs[k0 + 0][lrow + 64] = b1.x; Bs[k0 + 1][lrow + 64] = b1.y;
        Bs[k0 + 2][lrow + 64] = b1.z; Bs[k0 + 3][lrow + 64] = b1.w;
        __syncthreads();
#pragma unroll
        for (int k = 0; k < 16; k++) {
            const float4 av0 = *(const float4*)&As[k][ty * 8];
            const float4 av1 = *(const float4*)&As[k][ty * 8 + 4];
            const float4 bv0 = *(const float4*)&Bs[k][tx * 8];
            const float4 bv1 = *(const float4*)&Bs[k][tx * 8 + 4];
            const float a[8] = {av0.x, av0.y, av0.z, av0.w, av1.x, av1.y, av1.z, av1.w};
            const float b[8] = {bv0.x, bv0.y, bv0.z, bv0.w, bv1.x, bv1.y, bv1.z, bv1.w};
#pragma unroll
            for (int i = 0; i < 8; i++)
#pragma unroll
                for (int j = 0; j < 8; j++)
                    acc[i][j] = fmaf(a[i], b[j], acc[i][j]);
        }
    }
#pragma unroll
    for (int i = 0; i < 8; i++) {
        const int r = rowBase + ty * 8 + i;
        float4* p = (float4*)(dist + (size_t)r * NCOLS + colBase + tx * 8);
        p[0] = make_float4(acc[i][0], acc[i][1], acc[i][2], acc[i][3]);
        p[1] = make_float4(acc[i][4], acc[i][5], acc[i][6], acc[i][7]);
    }
#pragma unroll
    for (int i = 0; i < 8; i++) {
        float bv = acc[i][0];
        int   bj = 0;
#pragma unroll
        for (int j = 1; j < 8; j++)
            if (acc[i][j] > bv) { bv = acc[i][j]; bj = j; }
        const int lrowi = ty * 8 + i;
        redV[lrowi * 16 + tx] = bv;
        redI[lrowi * 16 + tx] = colBase + tx * 8 + bj;
    }
    __syncthreads();
    if (tid < BM) {
        float bv = redV[tid * 16];
        int   bi = redI[tid * 16];
#pragma unroll
        for (int t = 1; t < 16; t++) {
            const float v = redV[tid * 16 + t];
            if (v > bv) { bv = v; bi = redI[tid * 16 + t]; }
        }
        const int r = rowBase + tid;
        ws_val[(size_t)r * NCTILES + blockIdx.x] = bv;
        ws_idx[(size_t)r * NCTILES + blockIdx.x] = bi;
    }
}

// ---------------- kernel 2: final argmax across 64 tiles + gather ----------------
__global__ __launch_bounds__(64) void finalize_kernel(
    const float* __restrict__ ws_val,
    const int*   __restrict__ ws_idx,
    const float* __restrict__ embed,
    float* __restrict__ out_q,
    float* __restrict__ out_ind)
{
    const int r    = blockIdx.x;
    const int lane = threadIdx.x;

    float v = ws_val[(size_t)r * NCTILES + lane];
    int   i = ws_idx[(size_t)r * NCTILES + lane];

#pragma unroll
    for (int off = 32; off > 0; off >>= 1) {
        const float ov = __shfl_down(v, off);
        const int   oi = __shfl_down(i, off);
        if (ov > v || (ov == v && oi < i)) { v = ov; i = oi; }
    }
    i = __shfl(i, 0);

    if (lane == 0) out_ind[r] = (float)i;

    const float4* src = (const float4*)(embed + (size_t)i * KDIM);
    float4*       dst = (float4*)(out_q + (size_t)r * KDIM);
    dst[lane]      = src[lane];
    dst[lane + 64] = src[lane + 64];
}

extern "C" void kernel_launch(void* const* d_in, const int* in_sizes, int n_in,
                              void* d_out, int out_size, void* d_ws, size_t ws_size,
                              hipStream_t stream) {
    (void)in_sizes; (void)n_in; (void)out_size;
    const float* x     = (const float*)d_in[0];   // 8*2048*512
    const float* embed = (const float*)d_in[1];   // 8192*512

    float* out     = (float*)d_out;
    float* out_q   = out;                              // 8,388,608
    float* out_ind = out + (size_t)NROWS * KDIM;       // 16,384
    float* dist    = out_ind + NROWS;                  // 134,217,728

    const size_t abytes = (size_t)NROWS * KSPLIT * sizeof(unsigned short);  // 32 MB
    const size_t bbytes = (size_t)NCOLS * KSPLIT * sizeof(unsigned short);  // 16 MB
    const size_t wbytes = (size_t)NROWS * NCTILES * sizeof(float);          // 4 MB
    const size_t wsneed = abytes + bbytes + 2 * wbytes;                     // 56 MB

    if (ws_size >= wsneed) {
        unsigned short* Asp = (unsigned short*)d_ws;
        unsigned short* Bsp = (unsigned short*)((char*)d_ws + abytes);
        float* ws_val = (float*)((char*)d_ws + abytes + bbytes);
        int*   ws_idx = (int*)((char*)d_ws + abytes + bbytes + wbytes);

        split_kernel<<<NROWS + NCOLS, 128, 0, stream>>>(x, embed, Asp, Bsp);
        gemm_bf16_argmax<<<dim3(NCOLS / BN, NROWS / BM), 256, 0, stream>>>(
            Asp, Bsp, dist, ws_val, ws_idx);
        finalize_kernel<<<dim3(NROWS), dim3(64), 0, stream>>>(ws_val, ws_idx, embed, out_q, out_ind);
    } else {
        float* ws_val = (float*)d_ws;
        int*   ws_idx = (int*)((char*)d_ws + wbytes);
        gemm_argmax_f32<<<dim3(NCOLS / 128, NROWS / 128), 256, 0, stream>>>(
            x, embed, dist, ws_val, ws_idx);
        finalize_kernel<<<dim3(NROWS), dim3(64), 0, stream>>>(ws_val, ws_idx, embed, out_q, out_ind);
    }
}

// Round 2
// 966.450 us; speedup vs baseline: 2.0655x; 1.0051x over previous
//
#include <hip/hip_runtime.h>

// Problem: x (8,2048,512) f32, embed (1,8192,512) f32 (rows unit-norm).
// dist[r][c] = dot(x_row[r], embed[c])  -> (16384, 8192)
// ind[r] = argmax_c dist[r][c]
// outputs (concat f32): quantize = embed[ind] (8*2048*512) | ind as float (16384) | dist (16384*8192)
//
// fp32 GEMM on the bf16 matrix pipe via hi/lo split: a*b ~= ah*bh + ah*bl + al*bh.
// This version co-stages hi+lo per K-tile (48 MFMA per staging, 4:1 MFMA:ds_read),
// 2-buffer pipeline with counted vmcnt(8) across raw s_barriers (T3/T4),
// XOR-swizzled LDS chunks (T2, inverse-swizzled global source per rule #21),
// s_setprio around MFMA clusters (T5), bijective XCD blockIdx swizzle (T1).

#define NROWS   16384
#define NCOLS   8192
#define KDIM    512
#define KSPLIT  1024      // per-row split layout: [0,512)=hi, [512,1024)=lo (bf16)
#define NCTILES 64        // 8192 / 128

#define BM 128
#define BN 128

typedef float f32x4 __attribute__((ext_vector_type(4)));
typedef short s16x8 __attribute__((ext_vector_type(8)));

static __device__ __forceinline__ unsigned short f2bf_rne(float f) {
    unsigned u = __float_as_uint(f);
    u = (u + 0x7FFFu + ((u >> 16) & 1u)) >> 16;   // round-to-nearest-even
    return (unsigned short)u;
}
static __device__ __forceinline__ float bf2f(unsigned short h) {
    return __uint_as_float(((unsigned)h) << 16);
}

#define GLOAD_LDS16(g, l)                                                              \
    __builtin_amdgcn_global_load_lds((const __attribute__((address_space(1))) void*)(g), \
                                     (__attribute__((address_space(3))) void*)(l), 16, 0, 0)

// ---------------- kernel 0: fp32 -> (hi,lo) bf16 split ----------------
__global__ __launch_bounds__(128) void split_kernel(
    const float* __restrict__ x, const float* __restrict__ embed,
    unsigned short* __restrict__ A, unsigned short* __restrict__ B)
{
    int row = blockIdx.x;
    const float* src;
    unsigned short* dst;
    if (row < NROWS) { src = x + (size_t)row * KDIM;     dst = A + (size_t)row * KSPLIT; }
    else { row -= NROWS; src = embed + (size_t)row * KDIM; dst = B + (size_t)row * KSPLIT; }

    const int t = threadIdx.x;                 // 0..127, one float4 each
    const float4 v = ((const float4*)src)[t];
    const float f[4] = {v.x, v.y, v.z, v.w};
    unsigned short h[4], l[4];
#pragma unroll
    for (int i = 0; i < 4; i++) {
        h[i] = f2bf_rne(f[i]);
        l[i] = f2bf_rne(f[i] - bf2f(h[i]));
    }
    *(ushort4*)(dst + t * 4)        = make_ushort4(h[0], h[1], h[2], h[3]);
    *(ushort4*)(dst + KDIM + t * 4) = make_ushort4(l[0], l[1], l[2], l[3]);
}

// ---------------- kernel 1: pipelined bf16-split MFMA GEMM + fused argmax ----------------
// 256 threads = 4 waves (2x2), each wave computes a 64x64 sub-tile as 4x4 16x16 fragments.
// LDS tile layout: [128 rows][8 chunks of 8 bf16]; chunks 0-3 = hi k-window, 4-7 = lo.
// Swizzle: LDS(row, C) holds global chunk C ^ (row&7); reads use chunk ch ^ (lc&7).

// stage super-tile S (k-window S*32) into LDS buffer BUF (8 global_load_lds, 16B each)
#define STAGE(S, BUF) do {                                            \
    const int kb_ = (S) * 32;                                         \
    GLOAD_LDS16(Ag0 + kb_,              &As[BUF][t8]);                \
    GLOAD_LDS16(Ag0 + kb_ + 32*KSPLIT,  &As[BUF][t8 + 2048]);         \
    GLOAD_LDS16(Ag0 + kb_ + 64*KSPLIT,  &As[BUF][t8 + 4096]);         \
    GLOAD_LDS16(Ag0 + kb_ + 96*KSPLIT,  &As[BUF][t8 + 6144]);         \
    GLOAD_LDS16(Bg0 + kb_,              &Bs[BUF][t8]);                \
    GLOAD_LDS16(Bg0 + kb_ + 32*KSPLIT,  &Bs[BUF][t8 + 2048]);         \
    GLOAD_LDS16(Bg0 + kb_ + 64*KSPLIT,  &Bs[BUF][t8 + 4096]);         \
    GLOAD_LDS16(Bg0 + kb_ + 96*KSPLIT,  &Bs[BUF][t8 + 6144]);         \
} while (0)

// 3 products (hh, hl, lh) from buffer BUF: 48 MFMA, 16 ds_read_b128
#define COMPUTE(BUF) do {                                                              \
    s16x8 afh[4], bfh[4], bfl[4], afl[4];                                              \
    _Pragma("unroll")                                                                  \
    for (int m = 0; m < 4; m++)                                                        \
        afh[m] = *(const s16x8*)&As[BUF][(waveM*64 + m*16 + lc)*64 + sh];              \
    _Pragma("unroll")                                                                  \
    for (int n = 0; n < 4; n++)                                                        \
        bfh[n] = *(const s16x8*)&Bs[BUF][(waveN*64 + n*16 + lc)*64 + sh];              \
    __builtin_amdgcn_s_setprio(1);                                                     \
    _Pragma("unroll")                                                                  \
    for (int m = 0; m < 4; m++)                                                        \
        _Pragma("unroll")                                                              \
        for (int n = 0; n < 4; n++)                                                    \
            acc[m][n] = __builtin_amdgcn_mfma_f32_16x16x32_bf16(afh[m], bfh[n], acc[m][n], 0, 0, 0); \
    __builtin_amdgcn_s_setprio(0);                                                     \
    _Pragma("unroll")                                                                  \
    for (int n = 0; n < 4; n++)                                                        \
        bfl[n] = *(const s16x8*)&Bs[BUF][(waveN*64 + n*16 + lc)*64 + sl];              \
    __builtin_amdgcn_s_setprio(1);                                                     \
    _Pragma("unroll")                                                                  \
    for (int m = 0; m < 4; m++)                                                        \
        _Pragma("unroll")                                                              \
        for (int n = 0; n < 4; n++)                                                    \
            acc[m][n] = __builtin_amdgcn_mfma_f32_16x16x32_bf16(afh[m], bfl[n], acc[m][n], 0, 0, 0); \
    __builtin_amdgcn_s_setprio(0);                                                     \
    _Pragma("unroll")                                                                  \
    for (int m = 0; m < 4; m++)                                                        \
        afl[m] = *(const s16x8*)&As[BUF][(waveM*64 + m*16 + lc)*64 + sl];              \
    __builtin_amdgcn_s_setprio(1);                                                     \
    _Pragma("unroll")                                                                  \
    for (int m = 0; m < 4; m++)                                                        \
        _Pragma("unroll")                                                              \
        for (int n = 0; n < 4; n++)                                                    \
            acc[m][n] = __builtin_amdgcn_mfma_f32_16x16x32_bf16(afl[m], bfh[n], acc[m][n], 0, 0, 0); \
    __builtin_amdgcn_s_setprio(0);                                                     \
} while (0)

__global__ __launch_bounds__(256, 2) void gemm_bf16_pipe(
    const unsigned short* __restrict__ A,   // [16384][1024] bf16 (hi|lo)
    const unsigned short* __restrict__ B,   // [8192][1024]  bf16 (hi|lo)
    float* __restrict__ dist,               // [16384][8192]
    float* __restrict__ ws_val,             // [16384*64]
    int*   __restrict__ ws_idx)             // [16384*64]
{
    __shared__ unsigned short As[2][BM * 64];   // 2 x 16 KB
    __shared__ unsigned short Bs[2][BN * 64];   // 2 x 16 KB
    __shared__ float redV[BM * 2];
    __shared__ int   redI[BM * 2];

    const int tid   = threadIdx.x;
    const int lane  = tid & 63;
    const int wid   = tid >> 6;
    const int waveM = wid >> 1;             // 0..1
    const int waveN = wid & 1;              // 0..1
    const int q     = lane >> 4;            // 0..3 (k-chunk / C-row group)
    const int lc    = lane & 15;            // fragment row (A) / col (B,C)

    // bijective XCD swizzle: 8192 blocks, 8 XCDs -> each XCD gets 16 contiguous by-rows
    const int fid = blockIdx.y * 64 + blockIdx.x;
    const int swz = (fid & 7) * 1024 + (fid >> 3);
    const int bx  = swz & 63;
    const int by  = swz >> 6;
    const int rowBase = by * BM;
    const int colBase = bx * BN;

    // staging map (inverse-swizzled global source, linear LDS dest):
    // thread t covers LDS (row = l*32 + t>>3, chunk = t&7); data there = global chunk g
    const int g    = (tid & 7) ^ ((tid >> 3) & 7);
    const int goff = (g >> 2) * 512 + (g & 3) * 8;   // hi/lo segment + chunk offset
    const unsigned short* Ag0 = A + (size_t)(rowBase + (tid >> 3)) * KSPLIT + goff;
    const unsigned short* Bg0 = B + (size_t)(colBase + (tid >> 3)) * KSPLIT + goff;
    const int t8 = tid * 8;

    // swizzled read offsets (elements): logical chunk q (hi) / q+4 (lo), row&7 == lc&7
    const int sh = ((q        ^ (lc & 7)) << 3);
    const int sl = (((q | 4)  ^ (lc & 7)) << 3);

    f32x4 acc[4][4];
#pragma unroll
    for (int m = 0; m < 4; m++)
#pragma unroll
        for (int n = 0; n < 4; n++) acc[m][n] = (f32x4){0.f, 0.f, 0.f, 0.f};

    STAGE(0, 0);

#pragma unroll 1
    for (int s = 0; s < 16; s += 2) {
        // even step: compute buf0, prefetch s+1 -> buf1 (always valid: s+1 <= 15)
        STAGE(s + 1, 1);
        asm volatile("s_waitcnt vmcnt(8)" ::: "memory");   // tile s landed; s+1 in flight
        __builtin_amdgcn_s_barrier();
        asm volatile("" ::: "memory");
        COMPUTE(0);
        asm volatile("" ::: "memory");
        __builtin_amdgcn_s_barrier();

        // odd step: compute buf1, prefetch s+2 -> buf0
        if (s + 2 < 16) {
            STAGE(s + 2, 0);
            asm volatile("s_waitcnt vmcnt(8)" ::: "memory");
        } else {
            asm volatile("s_waitcnt vmcnt(0)" ::: "memory");
        }
        __builtin_amdgcn_s_barrier();
        asm volatile("" ::: "memory");
        COMPUTE(1);
        asm volatile("" ::: "memory");
        __builtin_amdgcn_s_barrier();
    }

    // ---- dist write: C/D layout col=lane&15, row=(lane>>4)*4+reg (m89/m91-verified) ----
#pragma unroll
    for (int m = 0; m < 4; m++) {
        const int r0 = rowBase + waveM * 64 + m * 16 + q * 4;
#pragma unroll
        for (int reg = 0; reg < 4; reg++) {
            float* dp = dist + (size_t)(r0 + reg) * NCOLS + colBase + waveN * 64 + lc;
#pragma unroll
            for (int n = 0; n < 4; n++)
                __builtin_nontemporal_store(acc[m][n][reg], dp + n * 16);
        }
    }

    // ---- fused argmax over the 128-col tile ----
#pragma unroll
    for (int m = 0; m < 4; m++) {
#pragma unroll
        for (int reg = 0; reg < 4; reg++) {
            float v = acc[m][0][reg];
            int   c = colBase + waveN * 64 + lc;          // n = 0
#pragma unroll
            for (int n = 1; n < 4; n++) {                 // ascending col => strict > keeps lowest idx
                const float vv = acc[m][n][reg];
                if (vv > v) { v = vv; c = colBase + waveN * 64 + n * 16 + lc; }
            }
#pragma unroll
            for (int off = 1; off < 16; off <<= 1) {
                const float ov = __shfl_xor(v, off);
                const int   oc = __shfl_xor(c, off);
                if (ov > v || (ov == v && oc < c)) { v = ov; c = oc; }
            }
            if (lc == 0) {
                const int tr = waveM * 64 + m * 16 + q * 4 + reg;   // 0..127
                redV[tr * 2 + waveN] = v;
                redI[tr * 2 + waveN] = c;
            }
        }
    }
    __syncthreads();

    if (tid < BM) {
        float v = redV[tid * 2]; int c = redI[tid * 2];
        const float v1 = redV[tid * 2 + 1];               // waveN=1 cols are always higher
        if (v1 > v) { v = v1; c = redI[tid * 2 + 1]; }
        const int r = rowBase + tid;
        ws_val[(size_t)r * NCTILES + bx] = v;
        ws_idx[(size_t)r * NCTILES + bx] = c;
    }
}

// ---------------- fallback: fp32 VALU GEMM (used only if ws too small) ----------------
__global__ __launch_bounds__(256, 2) void gemm_argmax_f32(
    const float* __restrict__ x, const float* __restrict__ embed,
    float* __restrict__ dist, float* __restrict__ ws_val, int* __restrict__ ws_idx)
{
    __shared__ float As[16][BM + 4];
    __shared__ float Bs[16][BN + 4];
    __shared__ float redV[BM * 16];
    __shared__ int   redI[BM * 16];

    const int tid = threadIdx.x;
    const int tx  = tid & 15;
    const int ty  = tid >> 4;
    const int rowBase = blockIdx.y * BM;
    const int colBase = blockIdx.x * BN;
    const int lrow = tid >> 2;
    const int lc   = tid & 3;

    const float* Aptr = x     + (size_t)(rowBase + lrow) * KDIM + lc * 4;
    const float* Bptr = embed + (size_t)(colBase + lrow) * KDIM + lc * 4;

    float acc[8][8];
#pragma unroll
    for (int i = 0; i < 8; i++)
#pragma unroll
        for (int j = 0; j < 8; j++) acc[i][j] = 0.0f;

    for (int kb = 0; kb < KDIM; kb += 16) {
        const float4 a0 = *(const float4*)(Aptr + kb);
        const float4 a1 = *(const float4*)(Aptr + kb + (size_t)64 * KDIM);
        const float4 b0 = *(const float4*)(Bptr + kb);
        const float4 b1 = *(const float4*)(Bptr + kb + (size_t)64 * KDIM);
        __syncthreads();
        const int k0 = lc * 4;
        As[k0 + 0][lrow] = a0.x; As[k0 + 1][lrow] = a0.y;
        As[k0 + 2][lrow] = a0.z; As[k0 + 3][lrow] = a0.w;
        As[k0 + 0][lrow + 64] = a1.x; As[k0 + 1][lrow + 64] = a1.y;
        As[k0 + 2][lrow + 64] = a1.z; As[k0 + 3][lrow + 64] = a1.w;
        Bs[k0 + 0][lrow] = b0.x; Bs[k0 + 1][lrow] = b0.y;
        Bs[k0 + 2][lrow] = b0.z; Bs[k0 + 3][lrow] = b0.w;
        Bs[k0 + 0][lrow + 64] = b1.x; Bs[k0 + 1][lrow + 64] = b1.y;
        Bs[k0 + 2][lrow + 64] = b1.z; Bs[k0 + 3][lrow + 64] = b1.w;
        __syncthreads();
#pragma unroll
        for (int k = 0; k < 16; k++) {
            const float4 av0 = *(const float4*)&As[k][ty * 8];
            const float4 av1 = *(const float4*)&As[k][ty * 8 + 4];
            const float4 bv0 = *(const float4*)&Bs[k][tx * 8];
            const float4 bv1 = *(const float4*)&Bs[k][tx * 8 + 4];
            const float a[8] = {av0.x, av0.y, av0.z, av0.w, av1.x, av1.y, av1.z, av1.w};
            const float b[8] = {bv0.x, bv0.y, bv0.z, bv0.w, bv1.x, bv1.y, bv1.z, bv1.w};
#pragma unroll
            for (int i = 0; i < 8; i++)
#pragma unroll
                for (int j = 0; j < 8; j++)
                    acc[i][j] = fmaf(a[i], b[j], acc[i][j]);
        }
    }
#pragma unroll
    for (int i = 0; i < 8; i++) {
        const int r = rowBase + ty * 8 + i;
        float4* p = (float4*)(dist + (size_t)r * NCOLS + colBase + tx * 8);
        p[0] = make_float4(acc[i][0], acc[i][1], acc[i][2], acc[i][3]);
        p[1] = make_float4(acc[i][4], acc[i][5], acc[i][6], acc[i][7]);
    }
#pragma unroll
    for (int i = 0; i < 8; i++) {
        float bv = acc[i][0];
        int   bj = 0;
#pragma unroll
        for (int j = 1; j < 8; j++)
            if (acc[i][j] > bv) { bv = acc[i][j]; bj = j; }
        const int lrowi = ty * 8 + i;
        redV[lrowi * 16 + tx] = bv;
        redI[lrowi * 16 + tx] = colBase + tx * 8 + bj;
    }
    __syncthreads();
    if (tid < BM) {
        float bv = redV[tid * 16];
        int   bi = redI[tid * 16];
#pragma unroll
        for (int t = 1; t < 16; t++) {
            const float v = redV[tid * 16 + t];
            if (v > bv) { bv = v; bi = redI[tid * 16 + t]; }
        }
        const int r = rowBase + tid;
        ws_val[(size_t)r * NCTILES + blockIdx.x] = bv;
        ws_idx[(size_t)r * NCTILES + blockIdx.x] = bi;
    }
}

// ---------------- kernel 2: final argmax across 64 tiles + gather ----------------
__global__ __launch_bounds__(64) void finalize_kernel(
    const float* __restrict__ ws_val,
    const int*   __restrict__ ws_idx,
    const float* __restrict__ embed,
    float* __restrict__ out_q,
    float* __restrict__ out_ind)
{
    const int r    = blockIdx.x;
    const int lane = threadIdx.x;

    float v = ws_val[(size_t)r * NCTILES + lane];
    int   i = ws_idx[(size_t)r * NCTILES + lane];

#pragma unroll
    for (int off = 32; off > 0; off >>= 1) {
        const float ov = __shfl_down(v, off);
        const int   oi = __shfl_down(i, off);
        if (ov > v || (ov == v && oi < i)) { v = ov; i = oi; }
    }
    i = __shfl(i, 0);

    if (lane == 0) out_ind[r] = (float)i;

    const float4* src = (const float4*)(embed + (size_t)i * KDIM);
    float4*       dst = (float4*)(out_q + (size_t)r * KDIM);
    dst[lane]      = src[lane];
    dst[lane + 64] = src[lane + 64];
}

extern "C" void kernel_launch(void* const* d_in, const int* in_sizes, int n_in,
                              void* d_out, int out_size, void* d_ws, size_t ws_size,
                              hipStream_t stream) {
    (void)in_sizes; (void)n_in; (void)out_size;
    const float* x     = (const float*)d_in[0];   // 8*2048*512
    const float* embed = (const float*)d_in[1];   // 8192*512

    float* out     = (float*)d_out;
    float* out_q   = out;                              // 8,388,608
    float* out_ind = out + (size_t)NROWS * KDIM;       // 16,384
    float* dist    = out_ind + NROWS;                  // 134,217,728

    const size_t abytes = (size_t)NROWS * KSPLIT * sizeof(unsigned short);  // 32 MB
    const size_t bbytes = (size_t)NCOLS * KSPLIT * sizeof(unsigned short);  // 16 MB
    const size_t wbytes = (size_t)NROWS * NCTILES * sizeof(float);          // 4 MB
    const size_t wsneed = abytes + bbytes + 2 * wbytes;                     // 56 MB

    if (ws_size >= wsneed) {
        unsigned short* Asp = (unsigned short*)d_ws;
        unsigned short* Bsp = (unsigned short*)((char*)d_ws + abytes);
        float* ws_val = (float*)((char*)d_ws + abytes + bbytes);
        int*   ws_idx = (int*)((char*)d_ws + abytes + bbytes + wbytes);

        split_kernel<<<NROWS + NCOLS, 128, 0, stream>>>(x, embed, Asp, Bsp);
        gemm_bf16_pipe<<<dim3(NCOLS / BN, NROWS / BM), 256, 0, stream>>>(
            Asp, Bsp, dist, ws_val, ws_idx);
        finalize_kernel<<<dim3(NROWS), dim3(64), 0, stream>>>(ws_val, ws_idx, embed, out_q, out_ind);
    } else {
        float* ws_val = (float*)d_ws;
        int*   ws_idx = (int*)((char*)d_ws + wbytes);
        gemm_argmax_f32<<<dim3(NCOLS / 128, NROWS / 128), 256, 0, stream>>>(
            x, embed, dist, ws_val, ws_idx);
        finalize_kernel<<<dim3(NROWS), dim3(64), 0, stream>>>(ws_val, ws_idx, embed, out_q, out_ind);
    }
}

// Round 3
// 925.985 us; speedup vs baseline: 2.1558x; 1.0437x over previous
//
#include <hip/hip_runtime.h>

// Problem: x (8,2048,512) f32, embed (1,8192,512) f32 (rows unit-norm).
// dist[r][c] = dot(x_row[r], embed[c])  -> (16384, 8192)
// ind[r] = argmax_c dist[r][c]
// outputs (concat f32): quantize = embed[ind] (8*2048*512) | ind as float (16384) | dist (16384*8192)
//
// fp32 GEMM on the bf16 matrix pipe via hi/lo split: a*b ~= ah*bh + ah*bl + al*bh.
// This round: m201-style 8-phase 256x256 tile, 8 waves (2Mx4N), per-wave 128x64,
// K-tile=32 with hi+lo co-staged (96 MFMA / 24 ds_read_b128 per wave per K-tile),
// 4 fine phases per K-tile {ds_read || global_load_lds stage || barrier || MFMA cluster},
// setprio around MFMA (T5 pays on phase-split schedules), XOR chunk swizzle (T2,
// verified round 2: conflicts 5e7->3e4). XCD swizzle REMOVED (round 2: 4x FETCH).

#define NROWS   16384
#define NCOLS   8192
#define KDIM    512
#define KSPLIT  1024      // per-row split layout: [0,512)=hi, [512,1024)=lo (bf16)

#define BM 256
#define BN 256
#define NCTILES 32        // 8192 / BN
#define NKT 16            // K-tiles of 32 (hi+lo co-staged)

typedef float f32x4 __attribute__((ext_vector_type(4)));
typedef short s16x8 __attribute__((ext_vector_type(8)));

static __device__ __forceinline__ unsigned short f2bf_rne(float f) {
    unsigned u = __float_as_uint(f);
    u = (u + 0x7FFFu + ((u >> 16) & 1u)) >> 16;   // round-to-nearest-even
    return (unsigned short)u;
}
static __device__ __forceinline__ float bf2f(unsigned short h) {
    return __uint_as_float(((unsigned)h) << 16);
}

#define GLOAD_LDS16(g, l)                                                              \
    __builtin_amdgcn_global_load_lds((const __attribute__((address_space(1))) void*)(g), \
                                     (__attribute__((address_space(3))) void*)(l), 16, 0, 0)

// ---------------- kernel 0: fp32 -> (hi,lo) bf16 split ----------------
__global__ __launch_bounds__(128) void split_kernel(
    const float* __restrict__ x, const float* __restrict__ embed,
    unsigned short* __restrict__ A, unsigned short* __restrict__ B)
{
    int row = blockIdx.x;
    const float* src;
    unsigned short* dst;
    if (row < NROWS) { src = x + (size_t)row * KDIM;     dst = A + (size_t)row * KSPLIT; }
    else { row -= NROWS; src = embed + (size_t)row * KDIM; dst = B + (size_t)row * KSPLIT; }

    const int t = threadIdx.x;                 // 0..127, one float4 each
    const float4 v = ((const float4*)src)[t];
    const float f[4] = {v.x, v.y, v.z, v.w};
    unsigned short h[4], l[4];
#pragma unroll
    for (int i = 0; i < 4; i++) {
        h[i] = f2bf_rne(f[i]);
        l[i] = f2bf_rne(f[i] - bf2f(h[i]));
    }
    *(ushort4*)(dst + t * 4)        = make_ushort4(h[0], h[1], h[2], h[3]);
    *(ushort4*)(dst + KDIM + t * 4) = make_ushort4(l[0], l[1], l[2], l[3]);
}

// ---------------- kernel 1: 256x256 8-phase bf16-split MFMA GEMM + fused argmax ----------------
// LDS tile: [256 rows][8 chunks of 8 bf16]; chunks 0-3 = hi k-window, 4-7 = lo.
// Swizzle: LDS(row, C) holds global chunk C ^ (row&7) (linear dest, pre-swizzled source).

// stage A (or B) tile of K-tile T into LDS buffer BUF: 4 x global_load_lds dwordx4 / thread
#define STAGE_A(T, BUF) do { const int kb_ = (T) * 32;                      \
    GLOAD_LDS16(Ag0 + kb_,                    &As[BUF][tid * 8]);           \
    GLOAD_LDS16(Ag0 + kb_ +  64 * KSPLIT,     &As[BUF][tid * 8 + 4096]);    \
    GLOAD_LDS16(Ag0 + kb_ + 128 * KSPLIT,     &As[BUF][tid * 8 + 8192]);    \
    GLOAD_LDS16(Ag0 + kb_ + 192 * KSPLIT,     &As[BUF][tid * 8 + 12288]);   \
} while (0)
#define STAGE_B(T, BUF) do { const int kb_ = (T) * 32;                      \
    GLOAD_LDS16(Bg0 + kb_,                    &Bs[BUF][tid * 8]);           \
    GLOAD_LDS16(Bg0 + kb_ +  64 * KSPLIT,     &Bs[BUF][tid * 8 + 4096]);    \
    GLOAD_LDS16(Bg0 + kb_ + 128 * KSPLIT,     &Bs[BUF][tid * 8 + 8192]);    \
    GLOAD_LDS16(Bg0 + kb_ + 192 * KSPLIT,     &Bs[BUF][tid * 8 + 12288]);   \
} while (0)

// load a-frags for m-pair starting at M0 from buffer pointer Ac
#define LOAD_A(M0) do {                                                          \
    ah[0] = *(const s16x8*)&Ac[(waveM * 128 + ((M0) + 0) * 16 + lc) * 64 + sh];  \
    al[0] = *(const s16x8*)&Ac[(waveM * 128 + ((M0) + 0) * 16 + lc) * 64 + sl];  \
    ah[1] = *(const s16x8*)&Ac[(waveM * 128 + ((M0) + 1) * 16 + lc) * 64 + sh];  \
    al[1] = *(const s16x8*)&Ac[(waveM * 128 + ((M0) + 1) * 16 + lc) * 64 + sl];  \
} while (0)

// 24 MFMA: m-pair M0, all 4 n-frags, terms hh + hl + lh
#define PHASE_MFMA(M0) do {                                                      \
    _Pragma("unroll")                                                            \
    for (int mm = 0; mm < 2; mm++) {                                             \
        _Pragma("unroll")                                                        \
        for (int n = 0; n < 4; n++)                                              \
            acc[(M0) + mm][n] = __builtin_amdgcn_mfma_f32_16x16x32_bf16(         \
                ah[mm], bh[n], acc[(M0) + mm][n], 0, 0, 0);                      \
        _Pragma("unroll")                                                        \
        for (int n = 0; n < 4; n++)                                              \
            acc[(M0) + mm][n] = __builtin_amdgcn_mfma_f32_16x16x32_bf16(         \
                ah[mm], bl[n], acc[(M0) + mm][n], 0, 0, 0);                      \
        _Pragma("unroll")                                                        \
        for (int n = 0; n < 4; n++)                                              \
            acc[(M0) + mm][n] = __builtin_amdgcn_mfma_f32_16x16x32_bf16(         \
                al[mm], bh[n], acc[(M0) + mm][n], 0, 0, 0);                      \
    }                                                                            \
} while (0)

#define PHASE_SYNC_PRE()  do { __builtin_amdgcn_s_barrier();                      \
    asm volatile("s_waitcnt lgkmcnt(0)" ::: "memory");                            \
    __builtin_amdgcn_s_setprio(1); } while (0)
#define PHASE_SYNC_POST() do { __builtin_amdgcn_s_setprio(0);                     \
    asm volatile("" ::: "memory");                                                \
    __builtin_amdgcn_s_barrier(); } while (0)

__global__ __launch_bounds__(512, 2) void gemm_bf16_8phase(
    const unsigned short* __restrict__ A,   // [16384][1024] bf16 (hi|lo)
    const unsigned short* __restrict__ B,   // [8192][1024]  bf16 (hi|lo)
    float* __restrict__ dist,               // [16384][8192]
    float* __restrict__ ws_val,             // [16384*32]
    int*   __restrict__ ws_idx)             // [16384*32]
{
    __shared__ unsigned short As[2][BM * 64];   // 2 x 32 KB
    __shared__ unsigned short Bs[2][BN * 64];   // 2 x 32 KB
    __shared__ float redV[BM * 4];              // 4 KB
    __shared__ int   redI[BM * 4];              // 4 KB

    const int tid   = threadIdx.x;              // 0..511
    const int lane  = tid & 63;
    const int wid   = tid >> 6;                 // 0..7
    const int waveM = wid >> 2;                 // 0..1 -> rows [waveM*128, +128)
    const int waveN = wid & 3;                  // 0..3 -> cols [waveN*64, +64)
    const int q     = lane >> 4;                // 0..3
    const int lc    = lane & 15;                // 0..15

    const int rowBase = blockIdx.y * BM;
    const int colBase = blockIdx.x * BN;

    // staging map: thread t covers LDS rows (t>>3) + {0,64,128,192}, chunk t&7.
    // content at (row, c) = global logical chunk c ^ (row&7); row&7 == (t>>3)&7 for all 4.
    const int srow = tid >> 3;                  // 0..63
    const int g    = (tid & 7) ^ (srow & 7);
    const int goff = (g >> 2) * 512 + (g & 3) * 8;   // hi/lo segment + chunk offset
    const unsigned short* Ag0 = A + (size_t)(rowBase + srow) * KSPLIT + goff;
    const unsigned short* Bg0 = B + (size_t)(colBase + srow) * KSPLIT + goff;

    // swizzled read offsets (elements) within a row: logical chunk q (hi) / q|4 (lo)
    const int sh = ((q       ^ (lc & 7)) << 3);
    const int sl = (((q | 4) ^ (lc & 7)) << 3);

    f32x4 acc[8][4];
#pragma unroll
    for (int m = 0; m < 8; m++)
#pragma unroll
        for (int n = 0; n < 4; n++) acc[m][n] = (f32x4){0.f, 0.f, 0.f, 0.f};

    // prologue: stage K-tile 0 into buf 0
    STAGE_A(0, 0);
    STAGE_B(0, 0);
    asm volatile("s_waitcnt vmcnt(0)" ::: "memory");
    __builtin_amdgcn_s_barrier();

#pragma unroll 1
    for (int t = 0; t < NKT; t++) {
        const int cur = t & 1, nxt = cur ^ 1;
        const unsigned short* Ac = &As[cur][0];
        const unsigned short* Bc = &Bs[cur][0];
        s16x8 bh[4], bl[4], ah[2], al[2];

        // ---- phase 0: b-frags (8 reads) + a-frags m0-1 (4) || stage A of t+1
#pragma unroll
        for (int n = 0; n < 4; n++) {
            bh[n] = *(const s16x8*)&Bc[(waveN * 64 + n * 16 + lc) * 64 + sh];
            bl[n] = *(const s16x8*)&Bc[(waveN * 64 + n * 16 + lc) * 64 + sl];
        }
        LOAD_A(0);
        if (t + 1 < NKT) STAGE_A(t + 1, nxt);
        PHASE_SYNC_PRE();
        PHASE_MFMA(0);
        PHASE_SYNC_POST();

        // ---- phase 1: a-frags m2-3 || stage B of t+1
        LOAD_A(2);
        if (t + 1 < NKT) STAGE_B(t + 1, nxt);
        PHASE_SYNC_PRE();
        PHASE_MFMA(2);
        PHASE_SYNC_POST();

        // ---- phase 2: a-frags m4-5
        LOAD_A(4);
        PHASE_SYNC_PRE();
        PHASE_MFMA(4);
        PHASE_SYNC_POST();

        // ---- phase 3: a-frags m6-7; tile boundary: wait t+1's 8 loads (issued 2-3 phases ago)
        LOAD_A(6);
        __builtin_amdgcn_s_barrier();
        asm volatile("s_waitcnt lgkmcnt(0)" ::: "memory");
        __builtin_amdgcn_s_setprio(1);
        PHASE_MFMA(6);
        __builtin_amdgcn_s_setprio(0);
        if (t + 1 < NKT) asm volatile("s_waitcnt vmcnt(0)" ::: "memory");
        asm volatile("" ::: "memory");
        __builtin_amdgcn_s_barrier();
    }

    // ---- dist write: C/D layout col=lane&15, row=(lane>>4)*4+reg (m89/m91-verified) ----
#pragma unroll
    for (int m = 0; m < 8; m++) {
        const int r0 = rowBase + waveM * 128 + m * 16 + q * 4;
#pragma unroll
        for (int reg = 0; reg < 4; reg++) {
            float* dp = dist + (size_t)(r0 + reg) * NCOLS + colBase + waveN * 64 + lc;
#pragma unroll
            for (int n = 0; n < 4; n++)
                __builtin_nontemporal_store(acc[m][n][reg], dp + n * 16);
        }
    }

    // ---- fused argmax over the 256-col tile ----
#pragma unroll
    for (int m = 0; m < 8; m++) {
#pragma unroll
        for (int reg = 0; reg < 4; reg++) {
            float v = acc[m][0][reg];
            int   c = colBase + waveN * 64 + lc;          // n = 0
#pragma unroll
            for (int n = 1; n < 4; n++) {                 // ascending col => strict > keeps lowest idx
                const float vv = acc[m][n][reg];
                if (vv > v) { v = vv; c = colBase + waveN * 64 + n * 16 + lc; }
            }
#pragma unroll
            for (int off = 1; off < 16; off <<= 1) {      // 16 lanes share this row
                const float ov = __shfl_xor(v, off);
                const int   oc = __shfl_xor(c, off);
                if (ov > v || (ov == v && oc < c)) { v = ov; c = oc; }
            }
            if (lc == 0) {
                const int tr = waveM * 128 + m * 16 + q * 4 + reg;   // 0..255
                redV[tr * 4 + waveN] = v;
                redI[tr * 4 + waveN] = c;
            }
        }
    }
    __syncthreads();

    if (tid < BM) {
        float v = redV[tid * 4]; int c = redI[tid * 4];
#pragma unroll
        for (int w = 1; w < 4; w++) {                     // ascending waveN = ascending cols
            const float vv = redV[tid * 4 + w];
            if (vv > v) { v = vv; c = redI[tid * 4 + w]; }
        }
        const int r = rowBase + tid;
        ws_val[(size_t)r * NCTILES + blockIdx.x] = v;
        ws_idx[(size_t)r * NCTILES + blockIdx.x] = c;
    }
}

// ---------------- fallback: fp32 VALU GEMM (used only if ws too small) ----------------
#define FB_NCT 64
__global__ __launch_bounds__(256, 2) void gemm_argmax_f32(
    const float* __restrict__ x, const float* __restrict__ embed,
    float* __restrict__ dist, float* __restrict__ ws_val, int* __restrict__ ws_idx)
{
    __shared__ float As[16][128 + 4];
    __shared__ float Bs[16][128 + 4];
    __shared__ float redV[128 * 16];
    __shared__ int   redI[128 * 16];

    const int tid = threadIdx.x;
    const int tx  = tid & 15;
    const int ty  = tid >> 4;
    const int rowBase = blockIdx.y * 128;
    const int colBase = blockIdx.x * 128;
    const int lrow = tid >> 2;
    const int lc   = tid & 3;

    const float* Aptr = x     + (size_t)(rowBase + lrow) * KDIM + lc * 4;
    const float* Bptr = embed + (size_t)(colBase + lrow) * KDIM + lc * 4;

    float acc[8][8];
#pragma unroll
    for (int i = 0; i < 8; i++)
#pragma unroll
        for (int j = 0; j < 8; j++) acc[i][j] = 0.0f;

    for (int kb = 0; kb < KDIM; kb += 16) {
        const float4 a0 = *(const float4*)(Aptr + kb);
        const float4 a1 = *(const float4*)(Aptr + kb + (size_t)64 * KDIM);
        const float4 b0 = *(const float4*)(Bptr + kb);
        const float4 b1 = *(const float4*)(Bptr + kb + (size_t)64 * KDIM);
        __syncthreads();
        const int k0 = lc * 4;
        As[k0 + 0][lrow] = a0.x; As[k0 + 1][lrow] = a0.y;
        As[k0 + 2][lrow] = a0.z; As[k0 + 3][lrow] = a0.w;
        As[k0 + 0][lrow + 64] = a1.x; As[k0 + 1][lrow + 64] = a1.y;
        As[k0 + 2][lrow + 64] = a1.z; As[k0 + 3][lrow + 64] = a1.w;
        Bs[k0 + 0][lrow] = b0.x; Bs[k0 + 1][lrow] = b0.y;
        Bs[k0 + 2][lrow] = b0.z; Bs[k0 + 3][lrow] = b0.w;
        Bs[k0 + 0][lrow + 64] = b1.x; Bs[k0 + 1][lrow + 64] = b1.y;
        Bs[k0 + 2][lrow + 64] = b1.z; Bs[k0 + 3][lrow + 64] = b1.w;
        __syncthreads();
#pragma unroll
        for (int k = 0; k < 16; k++) {
            const float4 av0 = *(const float4*)&As[k][ty * 8];
            const float4 av1 = *(const float4*)&As[k][ty * 8 + 4];
            const float4 bv0 = *(const float4*)&Bs[k][tx * 8];
            const float4 bv1 = *(const float4*)&Bs[k][tx * 8 + 4];
            const float a[8] = {av0.x, av0.y, av0.z, av0.w, av1.x, av1.y, av1.z, av1.w};
            const float b[8] = {bv0.x, bv0.y, bv0.z, bv0.w, bv1.x, bv1.y, bv1.z, bv1.w};
#pragma unroll
            for (int i = 0; i < 8; i++)
#pragma unroll
                for (int j = 0; j < 8; j++)
                    acc[i][j] = fmaf(a[i], b[j], acc[i][j]);
        }
    }
#pragma unroll
    for (int i = 0; i < 8; i++) {
        const int r = rowBase + ty * 8 + i;
        float4* p = (float4*)(dist + (size_t)r * NCOLS + colBase + tx * 8);
        p[0] = make_float4(acc[i][0], acc[i][1], acc[i][2], acc[i][3]);
        p[1] = make_float4(acc[i][4], acc[i][5], acc[i][6], acc[i][7]);
    }
#pragma unroll
    for (int i = 0; i < 8; i++) {
        float bv = acc[i][0];
        int   bj = 0;
#pragma unroll
        for (int j = 1; j < 8; j++)
            if (acc[i][j] > bv) { bv = acc[i][j]; bj = j; }
        const int lrowi = ty * 8 + i;
        redV[lrowi * 16 + tx] = bv;
        redI[lrowi * 16 + tx] = colBase + tx * 8 + bj;
    }
    __syncthreads();
    if (tid < 128) {
        float bv = redV[tid * 16];
        int   bi = redI[tid * 16];
#pragma unroll
        for (int t = 1; t < 16; t++) {
            const float v = redV[tid * 16 + t];
            if (v > bv) { bv = v; bi = redI[tid * 16 + t]; }
        }
        const int r = rowBase + tid;
        ws_val[(size_t)r * FB_NCT + blockIdx.x] = bv;
        ws_idx[(size_t)r * FB_NCT + blockIdx.x] = bi;
    }
}

// ---------------- kernel 2: final argmax across ntiles + gather ----------------
__global__ __launch_bounds__(64) void finalize_kernel(
    const float* __restrict__ ws_val,
    const int*   __restrict__ ws_idx,
    const float* __restrict__ embed,
    float* __restrict__ out_q,
    float* __restrict__ out_ind,
    int ntiles)
{
    const int r    = blockIdx.x;
    const int lane = threadIdx.x;

    float v; int i;
    if (lane < ntiles) {
        v = ws_val[(size_t)r * ntiles + lane];
        i = ws_idx[(size_t)r * ntiles + lane];
    } else {
        v = -__builtin_inff();
        i = 0x7FFFFFFF;
    }

#pragma unroll
    for (int off = 32; off > 0; off >>= 1) {
        const float ov = __shfl_down(v, off);
        const int   oi = __shfl_down(i, off);
        if (ov > v || (ov == v && oi < i)) { v = ov; i = oi; }
    }
    i = __shfl(i, 0);

    if (lane == 0) out_ind[r] = (float)i;

    const float4* src = (const float4*)(embed + (size_t)i * KDIM);
    float4*       dst = (float4*)(out_q + (size_t)r * KDIM);
    dst[lane]      = src[lane];
    dst[lane + 64] = src[lane + 64];
}

extern "C" void kernel_launch(void* const* d_in, const int* in_sizes, int n_in,
                              void* d_out, int out_size, void* d_ws, size_t ws_size,
                              hipStream_t stream) {
    (void)in_sizes; (void)n_in; (void)out_size;
    const float* x     = (const float*)d_in[0];   // 8*2048*512
    const float* embed = (const float*)d_in[1];   // 8192*512

    float* out     = (float*)d_out;
    float* out_q   = out;                              // 8,388,608
    float* out_ind = out + (size_t)NROWS * KDIM;       // 16,384
    float* dist    = out_ind + NROWS;                  // 134,217,728

    const size_t abytes = (size_t)NROWS * KSPLIT * sizeof(unsigned short);  // 32 MB
    const size_t bbytes = (size_t)NCOLS * KSPLIT * sizeof(unsigned short);  // 16 MB
    const size_t wbytes = (size_t)NROWS * NCTILES * sizeof(float);          // 2 MB
    const size_t wsneed = abytes + bbytes + 2 * wbytes;                     // 52 MB

    if (ws_size >= wsneed) {
        unsigned short* Asp = (unsigned short*)d_ws;
        unsigned short* Bsp = (unsigned short*)((char*)d_ws + abytes);
        float* ws_val = (float*)((char*)d_ws + abytes + bbytes);
        int*   ws_idx = (int*)((char*)d_ws + abytes + bbytes + wbytes);

        split_kernel<<<NROWS + NCOLS, 128, 0, stream>>>(x, embed, Asp, Bsp);
        gemm_bf16_8phase<<<dim3(NCOLS / BN, NROWS / BM), 512, 0, stream>>>(
            Asp, Bsp, dist, ws_val, ws_idx);
        finalize_kernel<<<dim3(NROWS), dim3(64), 0, stream>>>(
            ws_val, ws_idx, embed, out_q, out_ind, NCTILES);
    } else {
        float* ws_val = (float*)d_ws;
        int*   ws_idx = (int*)((char*)d_ws + (size_t)NROWS * FB_NCT * sizeof(float));
        gemm_argmax_f32<<<dim3(NCOLS / 128, NROWS / 128), 256, 0, stream>>>(
            x, embed, dist, ws_val, ws_idx);
        finalize_kernel<<<dim3(NROWS), dim3(64), 0, stream>>>(
            ws_val, ws_idx, embed, out_q, out_ind, FB_NCT);
    }
}